// Round 4
// baseline (368.250 us; speedup 1.0000x reference)
//
#include <hip/hip_runtime.h>
#include <stdint.h>

#define B_      4
#define S_      8
#define C_      1024
#define DK_     1024
#define MAXLEN_ 8192
#define SIZE_   4096   // token_ind + 1
#define NCH     64     // chunks per batch
#define CHR     64     // rows per chunk

typedef unsigned short ushort_t;
typedef unsigned int   uint_t;

__device__ __forceinline__ float bf2f(ushort_t u) {
    union { uint_t u; float f; } v; v.u = ((uint_t)u) << 16; return v.f;
}
__device__ __forceinline__ ushort_t f2bf(float f) {
    union { float f; uint_t u; } v; v.f = f;
    uint_t u = v.u;
    uint_t lsb = (u >> 16) & 1u;
    u += 0x7fffu + lsb;          // round-to-nearest-even
    return (ushort_t)(u >> 16);
}

// K1: qkv = x_last @ W + b.  q -> ws (fp32). k_new/v_new -> caches (fp32) at row tok.
__global__ void k_qkv(const float* __restrict__ x, const float* __restrict__ W,
                      const float* __restrict__ bias, float* __restrict__ kc,
                      float* __restrict__ vc, const int* __restrict__ tokp,
                      float* __restrict__ qws) {
    __shared__ float xs[C_];
    int b = blockIdx.y;
    int t = threadIdx.x;
    const float* xrow = x + (b * S_ + (S_ - 1)) * C_;
    for (int i = t; i < C_; i += 256) xs[i] = xrow[i];
    __syncthreads();
    int col = blockIdx.x * 256 + t;
    float acc = bias[col];
#pragma unroll 8
    for (int r = 0; r < C_; ++r)
        acc += xs[r] * W[r * (3 * DK_) + col];
    int tok = tokp[0];
    tok = tok < 0 ? 0 : (tok > MAXLEN_ - 1 ? MAXLEN_ - 1 : tok);   // safety clamp
    if (col < DK_) {
        qws[b * DK_ + col] = acc;
    } else if (col < 2 * DK_) {
        kc[((size_t)b * MAXLEN_ + tok) * DK_ + (col - DK_)] = acc;
    } else {
        vc[((size_t)b * MAXLEN_ + tok) * DK_ + (col - 2 * DK_)] = acc;
    }
}

// K2: w[b][j] = dot(q[b], K[b][j]) / 32.  4 waves/block, 8 rows/wave.
// Lane k-th float4 at offset k*256 + lane*4 -> consecutive lanes stride 16B (coalesced).
__global__ void k_scores(const float* __restrict__ kc, const float* __restrict__ qws,
                         float* __restrict__ w) {
    int b = blockIdx.y;
    int t = threadIdx.x;
    int wv = t >> 6;
    int lane = t & 63;
    const float* qp = qws + b * DK_ + lane * 4;
    float4 q0 = *(const float4*)(qp);
    float4 q1 = *(const float4*)(qp + 256);
    float4 q2 = *(const float4*)(qp + 512);
    float4 q3 = *(const float4*)(qp + 768);
    int j0 = blockIdx.x * 32 + wv * 8;
#pragma unroll 2
    for (int r = 0; r < 8; ++r) {
        int j = j0 + r;
        const float* kp = kc + ((size_t)b * MAXLEN_ + j) * DK_ + lane * 4;
        float4 k0 = *(const float4*)(kp);
        float4 k1 = *(const float4*)(kp + 256);
        float4 k2 = *(const float4*)(kp + 512);
        float4 k3 = *(const float4*)(kp + 768);
        float acc = k0.x * q0.x + k0.y * q0.y + k0.z * q0.z + k0.w * q0.w
                  + k1.x * q1.x + k1.y * q1.y + k1.z * q1.z + k1.w * q1.w
                  + k2.x * q2.x + k2.y * q2.y + k2.z * q2.z + k2.w * q2.w
                  + k3.x * q3.x + k3.y * q3.y + k3.z * q3.z + k3.w * q3.w;
        for (int off = 32; off > 0; off >>= 1) acc += __shfl_down(acc, off, 64);
        if (lane == 0) w[b * SIZE_ + j] = acc * 0.03125f;
    }
}

// K3: per batch: M = max(w); e = exp(w-M) in place; Epre[c] = exclusive prefix of chunk sums.
__global__ void k_prep(float* __restrict__ we, float* __restrict__ Epre) {
    __shared__ float red[256];
    __shared__ float csum[NCH];
    int b = blockIdx.x;
    int t = threadIdx.x;
    float* wb = we + b * SIZE_;
    float vals[16];
    float m = -1e30f;
#pragma unroll
    for (int k = 0; k < 16; ++k) { vals[k] = wb[t * 16 + k]; m = fmaxf(m, vals[k]); }
    red[t] = m;
    __syncthreads();
    for (int s = 128; s > 0; s >>= 1) {
        if (t < s) red[t] = fmaxf(red[t], red[t + s]);
        __syncthreads();
    }
    float M = red[0];
    __syncthreads();
    float ssum = 0.f;
#pragma unroll
    for (int k = 0; k < 16; ++k) {
        float e = __expf(vals[k] - M);
        wb[t * 16 + k] = e;
        ssum += e;
    }
    red[t] = ssum;
    __syncthreads();
    if (t < NCH) csum[t] = red[4 * t] + red[4 * t + 1] + red[4 * t + 2] + red[4 * t + 3];
    __syncthreads();
    if (t == 0) {
        float run = 0.f;
        for (int c = 0; c < NCH; ++c) { Epre[b * NCH + c] = run; run += csum[c]; }
    }
}

// K4: P[b][c][:] = sum_{j in chunk c} e_j * V[b][j][:]  (P stored bf16 to keep ws small)
__global__ void k_chunksum(const float* __restrict__ vc, const float* __restrict__ e,
                           ushort_t* __restrict__ P) {
    __shared__ float es[CHR];
    int b = blockIdx.y, c = blockIdx.x, t = threadIdx.x;
    if (t < CHR) es[t] = e[b * SIZE_ + c * CHR + t];
    __syncthreads();
    int d0 = t * 4;
    const float* vbase = vc + ((size_t)b * MAXLEN_ + c * CHR) * DK_ + d0;
    float a0 = 0, a1 = 0, a2 = 0, a3 = 0;
#pragma unroll 4
    for (int r = 0; r < CHR; ++r) {
        float4 u = *(const float4*)(vbase + (size_t)r * DK_);
        float ee = es[r];
        a0 += ee * u.x;
        a1 += ee * u.y;
        a2 += ee * u.z;
        a3 += ee * u.w;
    }
    ushort4 pv;
    pv.x = f2bf(a0); pv.y = f2bf(a1); pv.z = f2bf(a2); pv.w = f2bf(a3);
    *(ushort4*)(P + ((size_t)(b * NCH + c)) * DK_ + d0) = pv;
}

// K5: in-place exclusive prefix of P along chunk axis; one thread per (b, d).
__global__ void k_scan(ushort_t* __restrict__ P) {
    int b = blockIdx.y;
    int d = blockIdx.x * 256 + threadIdx.x;
    float run = 0.f;
    for (int c = 0; c < NCH; ++c) {
        ushort_t* p = P + ((size_t)(b * NCH + c)) * DK_ + d;
        float tmp = bf2f(*p);
        *p = f2bf(run);
        run += tmp;
    }
}

// K6: walk chunk rows: acc += e_j*V_j; S += e_j; out = acc/S (fp32).
__global__ void k_out(const float* __restrict__ vc, const float* __restrict__ e,
                      const float* __restrict__ Epre, const ushort_t* __restrict__ P,
                      float* __restrict__ out) {
    __shared__ float es[CHR];
    int b = blockIdx.y, c = blockIdx.x, t = threadIdx.x;
    if (t < CHR) es[t] = e[b * SIZE_ + c * CHR + t];
    __syncthreads();
    int d0 = t * 4;
    ushort4 pv = *(const ushort4*)(P + ((size_t)(b * NCH + c)) * DK_ + d0);
    float a0 = bf2f(pv.x), a1 = bf2f(pv.y), a2 = bf2f(pv.z), a3 = bf2f(pv.w);
    float S = Epre[b * NCH + c];
    const float* vbase = vc + ((size_t)b * MAXLEN_ + c * CHR) * DK_ + d0;
    float* obase = out + ((size_t)b * SIZE_ + c * CHR) * DK_ + d0;
#pragma unroll 4
    for (int r = 0; r < CHR; ++r) {
        float4 u = *(const float4*)(vbase + (size_t)r * DK_);
        float ee = es[r];
        a0 += ee * u.x;
        a1 += ee * u.y;
        a2 += ee * u.z;
        a3 += ee * u.w;
        S += ee;
        float inv = 1.0f / S;
        float4 ov = make_float4(a0 * inv, a1 * inv, a2 * inv, a3 * inv);
        *(float4*)(obase + (size_t)r * DK_) = ov;
    }
}

extern "C" void kernel_launch(void* const* d_in, const int* in_sizes, int n_in,
                              void* d_out, int out_size, void* d_ws, size_t ws_size,
                              hipStream_t stream) {
    const float* x    = (const float*)d_in[0];
    const float* W    = (const float*)d_in[1];
    const float* bias = (const float*)d_in[2];
    float* kc         = (float*)d_in[3];
    float* vc         = (float*)d_in[4];
    const int* tok    = (const int*)d_in[5];
    float* out        = (float*)d_out;

    // ws layout (floats):
    //   qws  @ 0       : 4*1024          (16 KB)
    //   we   @ 4096    : 4*4096          (64 KB)
    //   Epre @ 20480   : 4*64 (pad 256)  (1 KB)
    //   P    @ 20736   : bf16 4*64*1024  (512 KB)   -- total ~593 KB
    float* ws   = (float*)d_ws;
    float* qws  = ws;
    float* we   = ws + 4096;
    float* Epre = ws + 4096 + 16384;
    ushort_t* P = (ushort_t*)(ws + 4096 + 16384 + 256);

    hipLaunchKernelGGL(k_qkv,      dim3(12, 4),  dim3(256), 0, stream, x, W, bias, kc, vc, tok, qws);
    hipLaunchKernelGGL(k_scores,   dim3(128, 4), dim3(256), 0, stream, kc, qws, we);
    hipLaunchKernelGGL(k_prep,     dim3(4),      dim3(256), 0, stream, we, Epre);
    hipLaunchKernelGGL(k_chunksum, dim3(64, 4),  dim3(256), 0, stream, vc, we, P);
    hipLaunchKernelGGL(k_scan,     dim3(4, 4),   dim3(256), 0, stream, P);
    hipLaunchKernelGGL(k_out,      dim3(64, 4),  dim3(256), 0, stream, vc, we, Epre, P, out);
}